// Round 3
// baseline (78095.105 us; speedup 1.0000x reference)
//
#include <hip/hip_runtime.h>
#include <float.h>
#include <math.h>

#define BATCH 8
#define NPTS  2048
#define KNN   20
#define BN    (BATCH*NPTS)
#define SLOPE 0.2f
#define BNEPS 1e-5f

__device__ __forceinline__ float f4c(const float4& v, int cc) {
    return cc == 0 ? v.x : cc == 1 ? v.y : cc == 2 ? v.z : v.w;
}

// ---------------- xx: per-point squared norm ----------------
__global__ void xx_kernel(const float* __restrict__ x, float* __restrict__ xx, int C) {
    int p = blockIdx.x * 256 + threadIdx.x;           // p in [0, BN)
    int b = p >> 11, n = p & (NPTS - 1);
    const float* xb = x + (size_t)b * C * NPTS;
    float s = 0.f;
    for (int c = 0; c < C; ++c) { float v = xb[(size_t)c * NPTS + n]; s = fmaf(v, v, s); }
    xx[p] = s;
}

// ---------------- kNN v3: 32 rows x 1024 cands per block ----------------
// rank key: s = xx_c - 2*inner  (row-constant xx_r dropped; ordering unchanged)
template<int C>
__global__ __launch_bounds__(256, 4) void knn3_kernel(const float* __restrict__ x,
                                                      const float* __restrict__ xx,
                                                      float* __restrict__ pv,
                                                      int* __restrict__ pi) {
    constexpr int ROWS = 32, CHUNK = 256, HALF = 1024, NCH = HALF / CHUNK; // 4
    __shared__ union UU {
        struct { float xr[ROWS][64]; float dt[ROWS][CHUNK]; } s;          // 40960 B
        struct { float v[8][KNN][ROWS]; int i[8][KNN][ROWS]; } L;          // 40960 B
    } u;

    int t    = threadIdx.x;
    int b    = blockIdx.x >> 7;               // 128 blocks per batch
    int tile = (blockIdx.x >> 1) & 63;
    int half = blockIdx.x & 1;
    int r0   = tile * ROWS;
    int j0h  = half * HALF;
    const float* xb = x + (size_t)b * C * NPTS;

    // stage row features (coalesced global read; LDS write conflicts are one-time)
    for (int f = t; f < ROWS * C; f += 256) {
        int r = f & (ROWS - 1), c = f >> 5;
        u.s.xr[r][c] = xb[(size_t)c * NPTS + r0 + r];
    }

    float lv[KNN]; int li[KNN];
#pragma unroll
    for (int s = 0; s < KNN; ++s) { lv[s] = FLT_MAX; li[s] = 0x7fffffff; }

    int ty = t >> 5, tx = t & 31;     // compute: rows ty*4..+3, cols tx*8..+7
                                      // select : row tx, group ty (32 cols)
    __syncthreads();

    for (int ch = 0; ch < NCH; ++ch) {
        int j0 = j0h + ch * CHUNK;

        float acc[4][8];
#pragma unroll
        for (int i = 0; i < 4; ++i)
#pragma unroll
            for (int j = 0; j < 8; ++j) acc[i][j] = 0.f;

        const float* gx = xb + j0 + tx * 8;
        if constexpr (C >= 4) {
            for (int c4 = 0; c4 < C; c4 += 4) {
                float4 rv[4];
#pragma unroll
                for (int i = 0; i < 4; ++i)
                    rv[i] = *(const float4*)&u.s.xr[ty * 4 + i][c4];
#pragma unroll
                for (int cc = 0; cc < 4; ++cc) {
                    const float* col = gx + (size_t)(c4 + cc) * NPTS;
                    float4 a0 = *(const float4*)col;
                    float4 a1 = *(const float4*)(col + 4);
#pragma unroll
                    for (int i = 0; i < 4; ++i) {
                        float rvc = f4c(rv[i], cc);
                        acc[i][0] = fmaf(rvc, a0.x, acc[i][0]);
                        acc[i][1] = fmaf(rvc, a0.y, acc[i][1]);
                        acc[i][2] = fmaf(rvc, a0.z, acc[i][2]);
                        acc[i][3] = fmaf(rvc, a0.w, acc[i][3]);
                        acc[i][4] = fmaf(rvc, a1.x, acc[i][4]);
                        acc[i][5] = fmaf(rvc, a1.y, acc[i][5]);
                        acc[i][6] = fmaf(rvc, a1.z, acc[i][6]);
                        acc[i][7] = fmaf(rvc, a1.w, acc[i][7]);
                    }
                }
            }
        } else {
#pragma unroll
            for (int c = 0; c < C; ++c) {
                const float* col = gx + (size_t)c * NPTS;
                float4 a0 = *(const float4*)col;
                float4 a1 = *(const float4*)(col + 4);
#pragma unroll
                for (int i = 0; i < 4; ++i) {
                    float rvc = u.s.xr[ty * 4 + i][c];
                    acc[i][0] = fmaf(rvc, a0.x, acc[i][0]);
                    acc[i][1] = fmaf(rvc, a0.y, acc[i][1]);
                    acc[i][2] = fmaf(rvc, a0.z, acc[i][2]);
                    acc[i][3] = fmaf(rvc, a0.w, acc[i][3]);
                    acc[i][4] = fmaf(rvc, a1.x, acc[i][4]);
                    acc[i][5] = fmaf(rvc, a1.y, acc[i][5]);
                    acc[i][6] = fmaf(rvc, a1.z, acc[i][6]);
                    acc[i][7] = fmaf(rvc, a1.w, acc[i][7]);
                }
            }
        }

        // s-values -> dt
        float4 xq0 = *(const float4*)&xx[b * NPTS + j0 + tx * 8];
        float4 xq1 = *(const float4*)&xx[b * NPTS + j0 + tx * 8 + 4];
#pragma unroll
        for (int i = 0; i < 4; ++i) {
            float4 w0, w1;
            w0.x = xq0.x - 2.f * acc[i][0]; w0.y = xq0.y - 2.f * acc[i][1];
            w0.z = xq0.z - 2.f * acc[i][2]; w0.w = xq0.w - 2.f * acc[i][3];
            w1.x = xq1.x - 2.f * acc[i][4]; w1.y = xq1.y - 2.f * acc[i][5];
            w1.z = xq1.z - 2.f * acc[i][6]; w1.w = xq1.w - 2.f * acc[i][7];
            *(float4*)&u.s.dt[ty * 4 + i][tx * 8]     = w0;
            *(float4*)&u.s.dt[ty * 4 + i][tx * 8 + 4] = w1;
        }
        __syncthreads();

        // scan 32 candidates (rotated read order -> conflict-free), deferred inserts
        {
            int r = tx, g = ty;
            const float* drow = &u.s.dt[r][g * 32];
            float thr = lv[KNN - 1];
            unsigned mask = 0;
            int cc = r & 31;
            unsigned bit = 1u << cc;
#pragma unroll
            for (int m = 0; m < 32; ++m) {
                float v = drow[cc];
                mask |= (v < thr) ? bit : 0u;
                cc = (cc + 1) & 31;
                bit = (bit << 1) | (bit >> 31);
            }
            while (__any(mask != 0)) {
                if (mask) {
                    int mb = __ffs(mask) - 1;
                    mask &= mask - 1;
                    float v = drow[mb];
                    if (v < lv[KNN - 1]) {
                        lv[KNN - 1] = v; li[KNN - 1] = j0 + g * 32 + mb;
#pragma unroll
                        for (int s = KNN - 1; s > 0; --s) {
                            if (lv[s] < lv[s - 1]) {
                                float tv = lv[s]; lv[s] = lv[s - 1]; lv[s - 1] = tv;
                                int   ti = li[s]; li[s] = li[s - 1]; li[s - 1] = ti;
                            }
                        }
                    }
                }
            }
        }
        __syncthreads();                      // dt reuse fence
    }

    // dump per-thread lists (union re-use: dt/xr dead now)
    {
        int r = tx, g = ty;
#pragma unroll
        for (int s = 0; s < KNN; ++s) { u.L.v[g][s][r] = lv[s]; u.L.i[g][s][r] = li[s]; }
    }
    __syncthreads();

    if (t < ROWS) {
        int r = t;
        int pp[8]; float hv[8]; int hi[8];
#pragma unroll
        for (int g = 0; g < 8; ++g) { pp[g] = 0; hv[g] = u.L.v[g][0][r]; hi[g] = u.L.i[g][0][r]; }
        size_t base = ((size_t)(b * NPTS + r0 + r) * 2 + half) * KNN;
        for (int o = 0; o < KNN; ++o) {
            float bv = hv[0]; int bi = hi[0]; int bg = 0;
#pragma unroll
            for (int g = 1; g < 8; ++g)
                if (hv[g] < bv || (hv[g] == bv && hi[g] < bi)) { bv = hv[g]; bi = hi[g]; bg = g; }
            pv[base + o] = bv; pi[base + o] = bi;
#pragma unroll
            for (int g = 0; g < 8; ++g)
                if (bg == g) {
                    ++pp[g];
                    bool ok = pp[g] < KNN;
                    int q = ok ? pp[g] : KNN - 1;
                    float nv = u.L.v[g][q][r]; int ni = u.L.i[g][q][r];
                    hv[g] = ok ? nv : FLT_MAX;
                    hi[g] = ok ? ni : 0x7fffffff;
                }
        }
    }
}

// ---------------- merge two half-range top-20 lists ----------------
__global__ void knnmerge_kernel(const float* __restrict__ pv, const int* __restrict__ pi,
                                int* __restrict__ idx) {
    int p = blockIdx.x * 256 + threadIdx.x;   // [0, BN)
    size_t b0 = (size_t)p * 2 * KNN, b1 = b0 + KNN;
    int ia = 0, ib = 0;
    int* op = idx + (size_t)p * KNN;
    for (int o = 0; o < KNN; ++o) {
        float va = pv[b0 + ia], vb = pv[b1 + ib];
        int   ja = pi[b0 + ia], jb = pi[b1 + ib];
        bool takeA = (va < vb) || (va == vb && ja < jb);
        op[o] = takeA ? ja : jb;
        ia += takeA ? 1 : 0;
        ib += takeA ? 0 : 1;
    }
}

// ---------------- projection: y = x@Wtop, z = x@(Wbot-Wtop) ----------------
__global__ void proj_kernel(const float* __restrict__ x, const float* __restrict__ W,
                            float* __restrict__ y, float* __restrict__ z, int C, int Cout) {
    int p = blockIdx.x;
    int b = p >> 11, n = p & (NPTS - 1);
    int j = threadIdx.x;                      // j < Cout
    __shared__ float xc[64];
    if (j < C) xc[j] = x[(size_t)b * C * NPTS + (size_t)j * NPTS + n];
    __syncthreads();
    float sy = 0.f, sz = 0.f;
    for (int c = 0; c < C; ++c) {
        float xv = xc[c];
        float wt = W[c * Cout + j];
        float wb = W[(C + c) * Cout + j];
        sy = fmaf(xv, wt, sy);
        sz = fmaf(xv, wb - wt, sz);
    }
    y[(size_t)p * Cout + j] = sy;
    z[(size_t)p * Cout + j] = sz;
}

// ---------------- fused attention: one wave per point ----------------
template<int CO>
__global__ __launch_bounds__(256) void attn_kernel(const float* __restrict__ y,
                                                   const float* __restrict__ z,
                                                   const int* __restrict__ idx,
                                                   const float* __restrict__ a,
                                                   float* __restrict__ hout) {
    constexpr int NCH = CO / 64;
    constexpr int H   = CO / 4;
    int wv = threadIdx.x >> 6;
    int l  = threadIdx.x & 63;
    int p  = blockIdx.x * 4 + wv;             // b*N + n
    int b  = p >> 11;
    float hw[NCH][KNN], lg[NCH][KNN], zv[NCH], av[NCH];
#pragma unroll
    for (int q = 0; q < NCH; ++q) {
        int c = l + 64 * q;
        zv[q] = z[(size_t)p * CO + c];
        av[q] = a[(c & 3) * H + (c >> 2)];
    }
    const int* ip = idx + (size_t)p * KNN;
#pragma unroll
    for (int j = 0; j < KNN; ++j) {
        int m = ip[j];
        const float* yr = y + ((size_t)(b * NPTS) + m) * CO;
#pragma unroll
        for (int q = 0; q < NCH; ++q) {
            int c = l + 64 * q;
            float v = yr[c] + zv[q];
            hw[q][j] = v;
            float tt = v > 0.f ? v : v * SLOPE;
            float part = tt * av[q];
            part += __shfl_xor(part, 1);
            part += __shfl_xor(part, 2);
            lg[q][j] = part;
        }
    }
#pragma unroll
    for (int q = 0; q < NCH; ++q) {
        float mx = -FLT_MAX;
#pragma unroll
        for (int j = 0; j < KNN; ++j) mx = fmaxf(mx, lg[q][j]);
        float s = 0.f;
#pragma unroll
        for (int j = 0; j < KNN; ++j) { float e = expf(lg[q][j] - mx); lg[q][j] = e; s += e; }
        float inv = 1.f / s;
        float o = 0.f;
#pragma unroll
        for (int j = 0; j < KNN; ++j) o = fmaf(lg[q][j] * inv, hw[q][j], o);
        o = o > 0.f ? o : o * SLOPE;
        int c = l + 64 * q;
        hout[(size_t)p * CO + c] = o;
    }
}

// ---------------- BN stats, deterministic two-stage ----------------
__global__ void bnstatA_kernel(const float* __restrict__ h, float* __restrict__ part, int CO) {
    __shared__ float s1[256], s2[256];
    int g = blockIdx.x, t = threadIdx.x;
    int c = t & (CO - 1), sub = t / CO;
    int nsub = 256 / CO;
    const int ppb = BN / 64;                  // 256 points per block
    float a1 = 0.f, a2 = 0.f;
    for (int i = 0; i < ppb / nsub; ++i) {
        int p = g * ppb + sub + i * nsub;
        float v = h[(size_t)p * CO + c];
        a1 += v; a2 = fmaf(v, v, a2);
    }
    s1[t] = a1; s2[t] = a2;
    __syncthreads();
    if (sub == 0) {
        for (int k = 1; k < nsub; ++k) { a1 += s1[k * CO + c]; a2 += s2[k * CO + c]; }
        part[(size_t)g * CO + c]        = a1;
        part[(size_t)(64 + g) * CO + c] = a2;
    }
}

__global__ void bnstatB_kernel(const float* __restrict__ part, float* __restrict__ mu,
                               float* __restrict__ rstd, int CO) {
    int c = threadIdx.x;
    float s1 = 0.f, s2 = 0.f;
    for (int g = 0; g < 64; ++g) { s1 += part[(size_t)g * CO + c]; s2 += part[(size_t)(64 + g) * CO + c]; }
    float m   = s1 / (float)BN;
    float var = s2 / (float)BN - m * m;
    mu[c]   = m;
    rstd[c] = 1.f / sqrtf(var + BNEPS);
}

// ---------------- BN apply + leaky + transpose to (B,C,N) ----------------
template<int CO>
__global__ __launch_bounds__(256) void bnapply_kernel(const float* __restrict__ h,
                                                      const float* __restrict__ mu,
                                                      const float* __restrict__ rstd,
                                                      const float* __restrict__ gamma,
                                                      const float* __restrict__ beta,
                                                      float* __restrict__ xout) {
    __shared__ float tile[64][CO + 1];
    int g  = blockIdx.x;
    int p0 = g * 64;
    int b  = p0 >> 11, n0 = p0 & (NPTS - 1);
    int t  = threadIdx.x;
    for (int fi = t; fi < 64 * CO; fi += 256) {
        int pt = fi / CO, c = fi % CO;
        tile[pt][c] = h[(size_t)(p0 + pt) * CO + c];
    }
    __syncthreads();
    for (int fi = t; fi < 64 * CO; fi += 256) {
        int c = fi >> 6, nn = fi & 63;
        float v = tile[nn][c];
        v = (v - mu[c]) * rstd[c] * gamma[c] + beta[c];
        v = v > 0.f ? v : v * SLOPE;
        xout[((size_t)b * CO + c) * NPTS + n0 + nn] = v;
    }
}

// ---------------- host ----------------
static void run_layer(const float* xin, const float* W, const float* a,
                      const float* gm, const float* bt, float* xout, int C, int CO,
                      float* xx, float* pv, int* pi, int* idx, float* y, float* z, float* h,
                      float* part, float* mu, float* rstd, hipStream_t stream) {
    xx_kernel<<<BN / 256, 256, 0, stream>>>(xin, xx, C);
    if (C == 3)
        knn3_kernel<3><<<BATCH * 128, 256, 0, stream>>>(xin, xx, pv, pi);
    else
        knn3_kernel<64><<<BATCH * 128, 256, 0, stream>>>(xin, xx, pv, pi);
    knnmerge_kernel<<<BN / 256, 256, 0, stream>>>(pv, pi, idx);
    proj_kernel<<<BN, CO, 0, stream>>>(xin, W, y, z, C, CO);
    if (CO == 64)
        attn_kernel<64><<<BN / 4, 256, 0, stream>>>(y, z, idx, a, h);
    else
        attn_kernel<128><<<BN / 4, 256, 0, stream>>>(y, z, idx, a, h);
    bnstatA_kernel<<<64, 256, 0, stream>>>(h, part, CO);
    bnstatB_kernel<<<1, CO, 0, stream>>>(part, mu, rstd, CO);
    if (CO == 64)
        bnapply_kernel<64><<<BN / 64, 256, 0, stream>>>(h, mu, rstd, gm, bt, xout);
    else
        bnapply_kernel<128><<<BN / 64, 256, 0, stream>>>(h, mu, rstd, gm, bt, xout);
}

extern "C" void kernel_launch(void* const* d_in, const int* in_sizes, int n_in,
                              void* d_out, int out_size, void* d_ws, size_t ws_size,
                              hipStream_t stream) {
    const float* x  = (const float*)d_in[0];
    const float* W[3]  = {(const float*)d_in[1], (const float*)d_in[5], (const float*)d_in[9]};
    const float* a[3]  = {(const float*)d_in[2], (const float*)d_in[6], (const float*)d_in[10]};
    const float* gm[3] = {(const float*)d_in[3], (const float*)d_in[7], (const float*)d_in[11]};
    const float* bt[3] = {(const float*)d_in[4], (const float*)d_in[8], (const float*)d_in[12]};

    char* base = (char*)d_ws;
    size_t off = 0;
    auto carve = [&](size_t bytes) -> void* {
        void* r = base + off;
        off = (off + bytes + 255) & ~(size_t)255;
        return r;
    };
    float* xx   = (float*)carve((size_t)BN * sizeof(float));
    float* pv   = (float*)carve((size_t)BN * 2 * KNN * sizeof(float));
    int*   pi   = (int*)  carve((size_t)BN * 2 * KNN * sizeof(int));
    int*   idx  = (int*)  carve((size_t)BN * KNN * sizeof(int));
    float* y    = (float*)carve((size_t)BN * 128 * sizeof(float));
    float* z    = (float*)carve((size_t)BN * 128 * sizeof(float));
    float* h    = (float*)carve((size_t)BN * 128 * sizeof(float));
    float* part = (float*)carve((size_t)128 * 128 * sizeof(float));
    float* mu   = (float*)carve(128 * sizeof(float));
    float* rstd = (float*)carve(128 * sizeof(float));
    float* x1   = (float*)carve((size_t)BATCH * 64 * NPTS * sizeof(float));
    float* x2   = (float*)carve((size_t)BATCH * 64 * NPTS * sizeof(float));
    float* out  = (float*)d_out;

    run_layer(x,  W[0], a[0], gm[0], bt[0], x1,  3,  64, xx, pv, pi, idx, y, z, h, part, mu, rstd, stream);
    run_layer(x1, W[1], a[1], gm[1], bt[1], x2,  64, 64, xx, pv, pi, idx, y, z, h, part, mu, rstd, stream);
    run_layer(x2, W[2], a[2], gm[2], bt[2], out, 64, 128, xx, pv, pi, idx, y, z, h, part, mu, rstd, stream);
}

// Round 4
// 1029.201 us; speedup vs baseline: 75.8793x; 75.8793x over previous
//
#include <hip/hip_runtime.h>
#include <float.h>
#include <math.h>

#define BATCH 8
#define NPTS  2048
#define KNN   20
#define BN    (BATCH*NPTS)
#define SLOPE 0.2f
#define BNEPS 1e-5f

__device__ __forceinline__ float f4c(const float4& v, int cc) {
    return cc == 0 ? v.x : cc == 1 ? v.y : cc == 2 ? v.z : v.w;
}

// ---------------- xx: per-point squared norm ----------------
__global__ void xx_kernel(const float* __restrict__ x, float* __restrict__ xx, int C) {
    int p = blockIdx.x * 256 + threadIdx.x;           // p in [0, BN)
    int b = p >> 11, n = p & (NPTS - 1);
    const float* xb = x + (size_t)b * C * NPTS;
    float s = 0.f;
    for (int c = 0; c < C; ++c) { float v = xb[(size_t)c * NPTS + n]; s = fmaf(v, v, s); }
    xx[p] = s;
}

// ---------------- kNN v3b: 32 rows x 1024 cands per block ----------------
// rank key: s = xx_c - 2*inner  (row-constant xx_r dropped; ordering unchanged)
// NOTE: plain __launch_bounds__(256) — the (256,4) variant clamped VGPRs to 64
// and spilled lv/li/acc to scratch (164 GB HBM fetch/dispatch, 860x slowdown).
template<int C>
__global__ __launch_bounds__(256) void knn3_kernel(const float* __restrict__ x,
                                                   const float* __restrict__ xx,
                                                   float* __restrict__ pv,
                                                   int* __restrict__ pi) {
    constexpr int ROWS = 32, CHUNK = 256, HALF = 1024, NCH = HALF / CHUNK; // 4
    __shared__ union UU {
        struct { float xr[ROWS][64]; float dt[ROWS][CHUNK]; } s;          // 40960 B
        struct { float v[8][KNN][ROWS]; int i[8][KNN][ROWS]; } L;          // 40960 B
    } u;

    int t    = threadIdx.x;
    int b    = blockIdx.x >> 7;               // 128 blocks per batch
    int tile = (blockIdx.x >> 1) & 63;
    int half = blockIdx.x & 1;
    int r0   = tile * ROWS;
    int j0h  = half * HALF;
    const float* xb = x + (size_t)b * C * NPTS;

    // stage row features (coalesced global read; LDS write conflicts are one-time)
    for (int f = t; f < ROWS * C; f += 256) {
        int r = f & (ROWS - 1), c = f >> 5;
        u.s.xr[r][c] = xb[(size_t)c * NPTS + r0 + r];
    }

    float lv[KNN]; int li[KNN];
#pragma unroll
    for (int s = 0; s < KNN; ++s) { lv[s] = FLT_MAX; li[s] = 0x7fffffff; }

    int ty = t >> 5, tx = t & 31;     // compute: rows ty*4..+3, cols tx*8..+7
                                      // select : row tx, group ty (32 cols)
    __syncthreads();

    for (int ch = 0; ch < NCH; ++ch) {
        int j0 = j0h + ch * CHUNK;

        float acc[4][8];
#pragma unroll
        for (int i = 0; i < 4; ++i)
#pragma unroll
            for (int j = 0; j < 8; ++j) acc[i][j] = 0.f;

        const float* gx = xb + j0 + tx * 8;
        if constexpr (C >= 4) {
            for (int c4 = 0; c4 < C; c4 += 4) {
                float4 rv[4];
#pragma unroll
                for (int i = 0; i < 4; ++i)
                    rv[i] = *(const float4*)&u.s.xr[ty * 4 + i][c4];
#pragma unroll
                for (int cc = 0; cc < 4; ++cc) {
                    const float* col = gx + (size_t)(c4 + cc) * NPTS;
                    float4 a0 = *(const float4*)col;
                    float4 a1 = *(const float4*)(col + 4);
#pragma unroll
                    for (int i = 0; i < 4; ++i) {
                        float rvc = f4c(rv[i], cc);
                        acc[i][0] = fmaf(rvc, a0.x, acc[i][0]);
                        acc[i][1] = fmaf(rvc, a0.y, acc[i][1]);
                        acc[i][2] = fmaf(rvc, a0.z, acc[i][2]);
                        acc[i][3] = fmaf(rvc, a0.w, acc[i][3]);
                        acc[i][4] = fmaf(rvc, a1.x, acc[i][4]);
                        acc[i][5] = fmaf(rvc, a1.y, acc[i][5]);
                        acc[i][6] = fmaf(rvc, a1.z, acc[i][6]);
                        acc[i][7] = fmaf(rvc, a1.w, acc[i][7]);
                    }
                }
            }
        } else {
#pragma unroll
            for (int c = 0; c < C; ++c) {
                const float* col = gx + (size_t)c * NPTS;
                float4 a0 = *(const float4*)col;
                float4 a1 = *(const float4*)(col + 4);
#pragma unroll
                for (int i = 0; i < 4; ++i) {
                    float rvc = u.s.xr[ty * 4 + i][c];
                    acc[i][0] = fmaf(rvc, a0.x, acc[i][0]);
                    acc[i][1] = fmaf(rvc, a0.y, acc[i][1]);
                    acc[i][2] = fmaf(rvc, a0.z, acc[i][2]);
                    acc[i][3] = fmaf(rvc, a0.w, acc[i][3]);
                    acc[i][4] = fmaf(rvc, a1.x, acc[i][4]);
                    acc[i][5] = fmaf(rvc, a1.y, acc[i][5]);
                    acc[i][6] = fmaf(rvc, a1.z, acc[i][6]);
                    acc[i][7] = fmaf(rvc, a1.w, acc[i][7]);
                }
            }
        }

        // s-values -> dt
        float4 xq0 = *(const float4*)&xx[b * NPTS + j0 + tx * 8];
        float4 xq1 = *(const float4*)&xx[b * NPTS + j0 + tx * 8 + 4];
#pragma unroll
        for (int i = 0; i < 4; ++i) {
            float4 w0, w1;
            w0.x = xq0.x - 2.f * acc[i][0]; w0.y = xq0.y - 2.f * acc[i][1];
            w0.z = xq0.z - 2.f * acc[i][2]; w0.w = xq0.w - 2.f * acc[i][3];
            w1.x = xq1.x - 2.f * acc[i][4]; w1.y = xq1.y - 2.f * acc[i][5];
            w1.z = xq1.z - 2.f * acc[i][6]; w1.w = xq1.w - 2.f * acc[i][7];
            *(float4*)&u.s.dt[ty * 4 + i][tx * 8]     = w0;
            *(float4*)&u.s.dt[ty * 4 + i][tx * 8 + 4] = w1;
        }
        __syncthreads();

        // scan 32 candidates (rotated read order -> conflict-free), deferred inserts
        {
            int r = tx, g = ty;
            const float* drow = &u.s.dt[r][g * 32];
            float thr = lv[KNN - 1];
            unsigned mask = 0;
            int cc = r & 31;
            unsigned bit = 1u << cc;
#pragma unroll
            for (int m = 0; m < 32; ++m) {
                float v = drow[cc];
                mask |= (v < thr) ? bit : 0u;
                cc = (cc + 1) & 31;
                bit = (bit << 1) | (bit >> 31);
            }
            while (__any(mask != 0)) {
                if (mask) {
                    int mb = __ffs(mask) - 1;
                    mask &= mask - 1;
                    float v = drow[mb];
                    if (v < lv[KNN - 1]) {
                        lv[KNN - 1] = v; li[KNN - 1] = j0 + g * 32 + mb;
#pragma unroll
                        for (int s = KNN - 1; s > 0; --s) {
                            if (lv[s] < lv[s - 1]) {
                                float tv = lv[s]; lv[s] = lv[s - 1]; lv[s - 1] = tv;
                                int   ti = li[s]; li[s] = li[s - 1]; li[s - 1] = ti;
                            }
                        }
                    }
                }
            }
        }
        __syncthreads();                      // dt reuse fence
    }

    // dump per-thread lists (union re-use: dt/xr dead now)
    {
        int r = tx, g = ty;
#pragma unroll
        for (int s = 0; s < KNN; ++s) { u.L.v[g][s][r] = lv[s]; u.L.i[g][s][r] = li[s]; }
    }
    __syncthreads();

    if (t < ROWS) {
        int r = t;
        int pp[8]; float hv[8]; int hi[8];
#pragma unroll
        for (int g = 0; g < 8; ++g) { pp[g] = 0; hv[g] = u.L.v[g][0][r]; hi[g] = u.L.i[g][0][r]; }
        size_t base = ((size_t)(b * NPTS + r0 + r) * 2 + half) * KNN;
        for (int o = 0; o < KNN; ++o) {
            float bv = hv[0]; int bi = hi[0]; int bg = 0;
#pragma unroll
            for (int g = 1; g < 8; ++g)
                if (hv[g] < bv || (hv[g] == bv && hi[g] < bi)) { bv = hv[g]; bi = hi[g]; bg = g; }
            pv[base + o] = bv; pi[base + o] = bi;
#pragma unroll
            for (int g = 0; g < 8; ++g)
                if (bg == g) {
                    ++pp[g];
                    bool ok = pp[g] < KNN;
                    int q = ok ? pp[g] : KNN - 1;
                    float nv = u.L.v[g][q][r]; int ni = u.L.i[g][q][r];
                    hv[g] = ok ? nv : FLT_MAX;
                    hi[g] = ok ? ni : 0x7fffffff;
                }
        }
    }
}

// ---------------- merge two half-range top-20 lists ----------------
__global__ void knnmerge_kernel(const float* __restrict__ pv, const int* __restrict__ pi,
                                int* __restrict__ idx) {
    int p = blockIdx.x * 256 + threadIdx.x;   // [0, BN)
    size_t b0 = (size_t)p * 2 * KNN, b1 = b0 + KNN;
    int ia = 0, ib = 0;
    int* op = idx + (size_t)p * KNN;
    for (int o = 0; o < KNN; ++o) {
        float va = pv[b0 + ia], vb = pv[b1 + ib];
        int   ja = pi[b0 + ia], jb = pi[b1 + ib];
        bool takeA = (va < vb) || (va == vb && ja < jb);
        op[o] = takeA ? ja : jb;
        ia += takeA ? 1 : 0;
        ib += takeA ? 0 : 1;
    }
}

// ---------------- projection: y = x@Wtop, z = x@(Wbot-Wtop) ----------------
__global__ void proj_kernel(const float* __restrict__ x, const float* __restrict__ W,
                            float* __restrict__ y, float* __restrict__ z, int C, int Cout) {
    int p = blockIdx.x;
    int b = p >> 11, n = p & (NPTS - 1);
    int j = threadIdx.x;                      // j < Cout
    __shared__ float xc[64];
    if (j < C) xc[j] = x[(size_t)b * C * NPTS + (size_t)j * NPTS + n];
    __syncthreads();
    float sy = 0.f, sz = 0.f;
    for (int c = 0; c < C; ++c) {
        float xv = xc[c];
        float wt = W[c * Cout + j];
        float wb = W[(C + c) * Cout + j];
        sy = fmaf(xv, wt, sy);
        sz = fmaf(xv, wb - wt, sz);
    }
    y[(size_t)p * Cout + j] = sy;
    z[(size_t)p * Cout + j] = sz;
}

// ---------------- fused attention: one wave per point ----------------
template<int CO>
__global__ __launch_bounds__(256) void attn_kernel(const float* __restrict__ y,
                                                   const float* __restrict__ z,
                                                   const int* __restrict__ idx,
                                                   const float* __restrict__ a,
                                                   float* __restrict__ hout) {
    constexpr int NCH = CO / 64;
    constexpr int H   = CO / 4;
    int wv = threadIdx.x >> 6;
    int l  = threadIdx.x & 63;
    int p  = blockIdx.x * 4 + wv;             // b*N + n
    int b  = p >> 11;
    float hw[NCH][KNN], lg[NCH][KNN], zv[NCH], av[NCH];
#pragma unroll
    for (int q = 0; q < NCH; ++q) {
        int c = l + 64 * q;
        zv[q] = z[(size_t)p * CO + c];
        av[q] = a[(c & 3) * H + (c >> 2)];
    }
    const int* ip = idx + (size_t)p * KNN;
#pragma unroll
    for (int j = 0; j < KNN; ++j) {
        int m = ip[j];
        const float* yr = y + ((size_t)(b * NPTS) + m) * CO;
#pragma unroll
        for (int q = 0; q < NCH; ++q) {
            int c = l + 64 * q;
            float v = yr[c] + zv[q];
            hw[q][j] = v;
            float tt = v > 0.f ? v : v * SLOPE;
            float part = tt * av[q];
            part += __shfl_xor(part, 1);
            part += __shfl_xor(part, 2);
            lg[q][j] = part;
        }
    }
#pragma unroll
    for (int q = 0; q < NCH; ++q) {
        float mx = -FLT_MAX;
#pragma unroll
        for (int j = 0; j < KNN; ++j) mx = fmaxf(mx, lg[q][j]);
        float s = 0.f;
#pragma unroll
        for (int j = 0; j < KNN; ++j) { float e = expf(lg[q][j] - mx); lg[q][j] = e; s += e; }
        float inv = 1.f / s;
        float o = 0.f;
#pragma unroll
        for (int j = 0; j < KNN; ++j) o = fmaf(lg[q][j] * inv, hw[q][j], o);
        o = o > 0.f ? o : o * SLOPE;
        int c = l + 64 * q;
        hout[(size_t)p * CO + c] = o;
    }
}

// ---------------- BN stats, deterministic two-stage ----------------
__global__ void bnstatA_kernel(const float* __restrict__ h, float* __restrict__ part, int CO) {
    __shared__ float s1[256], s2[256];
    int g = blockIdx.x, t = threadIdx.x;
    int c = t & (CO - 1), sub = t / CO;
    int nsub = 256 / CO;
    const int ppb = BN / 64;                  // 256 points per block
    float a1 = 0.f, a2 = 0.f;
    for (int i = 0; i < ppb / nsub; ++i) {
        int p = g * ppb + sub + i * nsub;
        float v = h[(size_t)p * CO + c];
        a1 += v; a2 = fmaf(v, v, a2);
    }
    s1[t] = a1; s2[t] = a2;
    __syncthreads();
    if (sub == 0) {
        for (int k = 1; k < nsub; ++k) { a1 += s1[k * CO + c]; a2 += s2[k * CO + c]; }
        part[(size_t)g * CO + c]        = a1;
        part[(size_t)(64 + g) * CO + c] = a2;
    }
}

__global__ void bnstatB_kernel(const float* __restrict__ part, float* __restrict__ mu,
                               float* __restrict__ rstd, int CO) {
    int c = threadIdx.x;
    float s1 = 0.f, s2 = 0.f;
    for (int g = 0; g < 64; ++g) { s1 += part[(size_t)g * CO + c]; s2 += part[(size_t)(64 + g) * CO + c]; }
    float m   = s1 / (float)BN;
    float var = s2 / (float)BN - m * m;
    mu[c]   = m;
    rstd[c] = 1.f / sqrtf(var + BNEPS);
}

// ---------------- BN apply + leaky + transpose to (B,C,N) ----------------
template<int CO>
__global__ __launch_bounds__(256) void bnapply_kernel(const float* __restrict__ h,
                                                      const float* __restrict__ mu,
                                                      const float* __restrict__ rstd,
                                                      const float* __restrict__ gamma,
                                                      const float* __restrict__ beta,
                                                      float* __restrict__ xout) {
    __shared__ float tile[64][CO + 1];
    int g  = blockIdx.x;
    int p0 = g * 64;
    int b  = p0 >> 11, n0 = p0 & (NPTS - 1);
    int t  = threadIdx.x;
    for (int fi = t; fi < 64 * CO; fi += 256) {
        int pt = fi / CO, c = fi % CO;
        tile[pt][c] = h[(size_t)(p0 + pt) * CO + c];
    }
    __syncthreads();
    for (int fi = t; fi < 64 * CO; fi += 256) {
        int c = fi >> 6, nn = fi & 63;
        float v = tile[nn][c];
        v = (v - mu[c]) * rstd[c] * gamma[c] + beta[c];
        v = v > 0.f ? v : v * SLOPE;
        xout[((size_t)b * CO + c) * NPTS + n0 + nn] = v;
    }
}

// ---------------- host ----------------
static void run_layer(const float* xin, const float* W, const float* a,
                      const float* gm, const float* bt, float* xout, int C, int CO,
                      float* xx, float* pv, int* pi, int* idx, float* y, float* z, float* h,
                      float* part, float* mu, float* rstd, hipStream_t stream) {
    xx_kernel<<<BN / 256, 256, 0, stream>>>(xin, xx, C);
    if (C == 3)
        knn3_kernel<3><<<BATCH * 128, 256, 0, stream>>>(xin, xx, pv, pi);
    else
        knn3_kernel<64><<<BATCH * 128, 256, 0, stream>>>(xin, xx, pv, pi);
    knnmerge_kernel<<<BN / 256, 256, 0, stream>>>(pv, pi, idx);
    proj_kernel<<<BN, CO, 0, stream>>>(xin, W, y, z, C, CO);
    if (CO == 64)
        attn_kernel<64><<<BN / 4, 256, 0, stream>>>(y, z, idx, a, h);
    else
        attn_kernel<128><<<BN / 4, 256, 0, stream>>>(y, z, idx, a, h);
    bnstatA_kernel<<<64, 256, 0, stream>>>(h, part, CO);
    bnstatB_kernel<<<1, CO, 0, stream>>>(part, mu, rstd, CO);
    if (CO == 64)
        bnapply_kernel<64><<<BN / 64, 256, 0, stream>>>(h, mu, rstd, gm, bt, xout);
    else
        bnapply_kernel<128><<<BN / 64, 256, 0, stream>>>(h, mu, rstd, gm, bt, xout);
}

extern "C" void kernel_launch(void* const* d_in, const int* in_sizes, int n_in,
                              void* d_out, int out_size, void* d_ws, size_t ws_size,
                              hipStream_t stream) {
    const float* x  = (const float*)d_in[0];
    const float* W[3]  = {(const float*)d_in[1], (const float*)d_in[5], (const float*)d_in[9]};
    const float* a[3]  = {(const float*)d_in[2], (const float*)d_in[6], (const float*)d_in[10]};
    const float* gm[3] = {(const float*)d_in[3], (const float*)d_in[7], (const float*)d_in[11]};
    const float* bt[3] = {(const float*)d_in[4], (const float*)d_in[8], (const float*)d_in[12]};

    char* base = (char*)d_ws;
    size_t off = 0;
    auto carve = [&](size_t bytes) -> void* {
        void* r = base + off;
        off = (off + bytes + 255) & ~(size_t)255;
        return r;
    };
    float* xx   = (float*)carve((size_t)BN * sizeof(float));
    float* pv   = (float*)carve((size_t)BN * 2 * KNN * sizeof(float));
    int*   pi   = (int*)  carve((size_t)BN * 2 * KNN * sizeof(int));
    int*   idx  = (int*)  carve((size_t)BN * KNN * sizeof(int));
    float* y    = (float*)carve((size_t)BN * 128 * sizeof(float));
    float* z    = (float*)carve((size_t)BN * 128 * sizeof(float));
    float* h    = (float*)carve((size_t)BN * 128 * sizeof(float));
    float* part = (float*)carve((size_t)128 * 128 * sizeof(float));
    float* mu   = (float*)carve(128 * sizeof(float));
    float* rstd = (float*)carve(128 * sizeof(float));
    float* x1   = (float*)carve((size_t)BATCH * 64 * NPTS * sizeof(float));
    float* x2   = (float*)carve((size_t)BATCH * 64 * NPTS * sizeof(float));
    float* out  = (float*)d_out;

    run_layer(x,  W[0], a[0], gm[0], bt[0], x1,  3,  64, xx, pv, pi, idx, y, z, h, part, mu, rstd, stream);
    run_layer(x1, W[1], a[1], gm[1], bt[1], x2,  64, 64, xx, pv, pi, idx, y, z, h, part, mu, rstd, stream);
    run_layer(x2, W[2], a[2], gm[2], bt[2], out, 64, 128, xx, pv, pi, idx, y, z, h, part, mu, rstd, stream);
}